// Round 11
// baseline (76.519 us; speedup 1.0000x reference)
//
#include <hip/hip_runtime.h>
#include <cmath>

namespace {
constexpr int B_ = 2, K_ = 4, D_ = 128, L_ = 4096, N_ = 16, R_ = 8, C_ = 40;
constexpr int CHUNK = 32, NCH = L_ / CHUNK;   // 128 chunks of 32
constexpr float LOG2E = 1.44269504f;
}

#if __has_builtin(__builtin_amdgcn_exp2f)
#define FEXP2(x) __builtin_amdgcn_exp2f(x)
#else
#define FEXP2(x) exp2f(x)
#endif

// ===========================================================================
// kP: projection GEMM, LDS-staged. Grid = 8 bk x 32 lt x 2 type = 512 blocks,
// 192 threads (3 waves), 2 blocks/CU (76 KB LDS). Type 0: kv -> dts(8)+B(16).
// Type 1: q -> C(16). Xs staged once (coalesced, each input read 1x from HBM);
// thread (cg,lp) computes 4ch x 4l: per-d 1 b128 x + 1 broadcast b128 w + 16 FMA.
// ===========================================================================
__global__ __launch_bounds__(192, 2) void kP_gemm(
    const float* __restrict__ qx, const float* __restrict__ kv,
    const float* __restrict__ xw,   // (K, 40, D)
    float* __restrict__ dtsT,       // (B,K,L,8)
    float* __restrict__ BT,         // (B,K,L,16)
    float* __restrict__ CT)         // (B,K,L,16)
{
    __shared__ float Xs[128 * 128];   // [d][l]  64 KB
    __shared__ float Ws[128 * 24];    // [d][c]  <=12 KB used

    const int tid = threadIdx.x;
    const int typ = blockIdx.x & 1;
    const int lt  = (blockIdx.x >> 1) & 31;
    const int bk  = blockIdx.x >> 6;
    const int k   = bk & 3;
    const float* X = typ ? qx : kv;

    // ---- stage Ws, c-fastest (conflict-light LDS writes; gather is L2/L3-hot)
    if (typ == 0) {
        for (int i = tid; i < 24 * D_; i += 192) {
            const int c = i % 24, d = i / 24;
            Ws[d * 24 + c] = xw[(k * C_ + c) * D_ + d];
        }
    } else {
        for (int i = tid; i < 16 * D_; i += 192) {
            const int c = i & 15, d = i >> 4;
            Ws[d * 16 + c] = xw[(k * C_ + 24 + c) * D_ + d];
        }
    }
    // ---- stage Xs: 4096 float4, coalesced 512B runs per row
    {
        const float* src = X + (size_t)bk * D_ * L_ + lt * 128;
        for (int f = tid; f < 4096; f += 192) {
            const int d = f >> 5, l4 = (f & 31) << 2;
            *(float4*)&Xs[d * 128 + l4] = *(const float4*)(src + (size_t)d * L_ + l4);
        }
    }
    __syncthreads();

    const int cg = tid >> 5;          // 0..5
    const int lp = tid & 31;          // 0..31
    const int NC = typ ? 16 : 24;
    if (cg * 4 < NC) {
        const int ch = cg * 4;
        float acc[4][4];              // [c][l]
        #pragma unroll
        for (int c = 0; c < 4; ++c)
            #pragma unroll
            for (int j = 0; j < 4; ++j) acc[c][j] = 0.f;

        #pragma unroll 4
        for (int d = 0; d < D_; ++d) {
            const float4 xv = *(const float4*)&Xs[d * 128 + lp * 4];
            const float4 wv = *(const float4*)&Ws[d * NC + ch];
            const float* xp = (const float*)&xv;
            const float* wp = (const float*)&wv;
            #pragma unroll
            for (int c = 0; c < 4; ++c)
                #pragma unroll
                for (int j = 0; j < 4; ++j)
                    acc[c][j] = fmaf(xp[j], wp[c], acc[c][j]);
        }

        const size_t base = (size_t)bk * L_ + lt * 128 + lp * 4;
        #pragma unroll
        for (int j = 0; j < 4; ++j) {
            float4 o; o.x = acc[0][j]; o.y = acc[1][j]; o.z = acc[2][j]; o.w = acc[3][j];
            if (typ)          *(float4*)(CT + (base + j) * N_ + ch) = o;
            else if (ch < 8)  *(float4*)(dtsT + (base + j) * R_ + ch) = o;
            else              *(float4*)(BT + (base + j) * N_ + (ch - 8)) = o;
        }
    }
}

// ---------------------------------------------------------------------------
// k2: chunk pass 1 (r7 verbatim). Thread = d, u direct from kv (contiguous).
// ---------------------------------------------------------------------------
__global__ __launch_bounds__(128, 1) void k2_pass1(
    const float* __restrict__ kv, const float* __restrict__ dtsT,
    const float* __restrict__ BT, const float* __restrict__ alg,
    const float* __restrict__ dtw, const float* __restrict__ dtb,
    float* __restrict__ hend, float* __restrict__ Ssum)
{
    __shared__ float dts_s[CHUNK * R_];   // 1 KB
    __shared__ float B_s[CHUNK * N_];     // 2 KB

    const int tid = threadIdx.x;
    const int d = tid;
    const int blk = blockIdx.x;
    const int ch = blk & (NCH - 1);
    const int bk = blk >> 7;
    const int k = bk & 3;

    {
        const float* src = dtsT + ((size_t)bk * L_ + ch * CHUNK) * R_;
        if (tid < 64) *(float4*)&dts_s[4 * tid] = *(const float4*)(src + 4 * tid);
        const float* bsrc = BT + ((size_t)bk * L_ + ch * CHUNK) * N_;
        *(float4*)&B_s[4 * tid] = *(const float4*)(bsrc + 4 * tid);
    }

    float uu[CHUNK];
    {
        const float4* up = (const float4*)(kv + ((size_t)bk * D_ + d) * L_ + ch * CHUNK);
        #pragma unroll
        for (int j = 0; j < 8; ++j) {
            const float4 v = up[j];
            uu[4*j] = v.x; uu[4*j+1] = v.y; uu[4*j+2] = v.z; uu[4*j+3] = v.w;
        }
    }

    float dtwr[R_];
    {
        const float* p = dtw + ((size_t)k * D_ + d) * R_;
        *(float4*)&dtwr[0] = *(const float4*)p;
        *(float4*)&dtwr[4] = *(const float4*)(p + 4);
    }
    const float bias = dtb[k * D_ + d];
    float A2[N_];
    {
        const float* ap = alg + ((size_t)k * D_ + d) * N_;
        #pragma unroll
        for (int j = 0; j < 4; ++j) {
            float4 a = *(const float4*)(ap + 4 * j);
            A2[4*j]   = -__expf(a.x) * LOG2E; A2[4*j+1] = -__expf(a.y) * LOG2E;
            A2[4*j+2] = -__expf(a.z) * LOG2E; A2[4*j+3] = -__expf(a.w) * LOG2E;
        }
    }
    __syncthreads();

    float h[N_];
    #pragma unroll
    for (int n = 0; n < N_; ++n) h[n] = 0.f;
    float sd = 0.f;

    #pragma unroll
    for (int l = 0; l < CHUNK; ++l) {
        float dv[R_];
        *(float4*)&dv[0] = *(const float4*)&dts_s[l * R_];
        *(float4*)&dv[4] = *(const float4*)&dts_s[l * R_ + 4];
        float s = bias;
        #pragma unroll
        for (int r = 0; r < R_; ++r) s = fmaf(dv[r], dtwr[r], s);
        const float e = FEXP2(s * LOG2E);
        const float dlt = (s > 15.f) ? s : __logf(1.f + e);
        sd += dlt;
        const float xb = dlt * uu[l];
        #pragma unroll
        for (int g = 0; g < 4; ++g) {
            const float4 bg = *(const float4*)&B_s[l * N_ + 4 * g];
            h[4*g+0] = fmaf(FEXP2(dlt * A2[4*g+0]), h[4*g+0], xb * bg.x);
            h[4*g+1] = fmaf(FEXP2(dlt * A2[4*g+1]), h[4*g+1], xb * bg.y);
            h[4*g+2] = fmaf(FEXP2(dlt * A2[4*g+2]), h[4*g+2], xb * bg.z);
            h[4*g+3] = fmaf(FEXP2(dlt * A2[4*g+3]), h[4*g+3], xb * bg.w);
        }
    }

    float* hp = hend + (((size_t)bk * NCH + ch) * D_ + d) * N_;
    #pragma unroll
    for (int j = 0; j < 4; ++j) {
        float4 o; o.x = h[4*j]; o.y = h[4*j+1]; o.z = h[4*j+2]; o.w = h[4*j+3];
        *(float4*)(hp + 4 * j) = o;
    }
    Ssum[((size_t)bk * NCH + ch) * D_ + d] = sd;
}

// ---------------------------------------------------------------------------
// k25: serial chunk chain (r7 verbatim).
// ---------------------------------------------------------------------------
__global__ __launch_bounds__(64, 2) void k25_chain(
    const float* __restrict__ alg, const float* __restrict__ Ssum,
    const float* __restrict__ hend, float* __restrict__ hinit)
{
    const int tg = blockIdx.x * 64 + threadIdx.x;   // 16384 threads
    const int n = tg & 15;
    const int d = (tg >> 4) & 127;
    const int bk = tg >> 11;
    const int k = bk & 3;

    const float A2 = -__expf(alg[((size_t)k * D_ + d) * N_ + n]) * LOG2E;
    float h = 0.f;
    for (int c0 = 0; c0 < NCH; c0 += 32) {
        float he[32], ss[32];
        #pragma unroll
        for (int j = 0; j < 32; ++j) {
            const size_t si = ((size_t)bk * NCH + c0 + j) * D_ + d;
            he[j] = hend[si * N_ + n];
            ss[j] = Ssum[si];
        }
        #pragma unroll
        for (int j = 0; j < 32; ++j) {
            const size_t si = ((size_t)bk * NCH + c0 + j) * D_ + d;
            hinit[si * N_ + n] = h;
            h = fmaf(FEXP2(ss[j] * A2), h, he[j]);
        }
    }
}

// ---------------------------------------------------------------------------
// k3: pass-2 (r7 verbatim). u direct from kv; y via stride-33 LDS transpose.
// ---------------------------------------------------------------------------
__global__ __launch_bounds__(128, 1) void k3_pass2(
    const float* __restrict__ kv, const float* __restrict__ dtsT,
    const float* __restrict__ BT, const float* __restrict__ CT,
    const float* __restrict__ alg, const float* __restrict__ dtw,
    const float* __restrict__ dtb, const float* __restrict__ DsG,
    const float* __restrict__ hinit, float* __restrict__ out)
{
    constexpr int YS = CHUNK + 1;
    __shared__ float dts_s[CHUNK * R_];
    __shared__ float B_s[CHUNK * N_];
    __shared__ float C_s[CHUNK * N_];
    __shared__ float y_s[D_ * YS];
    const int tid = threadIdx.x;
    const int d = tid;
    const int blk = blockIdx.x;
    const int ch = blk & (NCH - 1);
    const int bk = blk >> 7;
    const int k = bk & 3;

    {
        const float* src = dtsT + ((size_t)bk * L_ + ch * CHUNK) * R_;
        if (tid < 64) *(float4*)&dts_s[4 * tid] = *(const float4*)(src + 4 * tid);
        const float* bsrc = BT + ((size_t)bk * L_ + ch * CHUNK) * N_;
        *(float4*)&B_s[4 * tid] = *(const float4*)(bsrc + 4 * tid);
        const float* csrc = CT + ((size_t)bk * L_ + ch * CHUNK) * N_;
        *(float4*)&C_s[4 * tid] = *(const float4*)(csrc + 4 * tid);
    }
    float uu[CHUNK];
    {
        const float4* up = (const float4*)(kv + ((size_t)bk * D_ + d) * L_ + ch * CHUNK);
        #pragma unroll
        for (int j = 0; j < 8; ++j) {
            const float4 v = up[j];
            uu[4*j] = v.x; uu[4*j+1] = v.y; uu[4*j+2] = v.z; uu[4*j+3] = v.w;
        }
    }
    float dtwr[R_];
    {
        const float* p = dtw + ((size_t)k * D_ + d) * R_;
        *(float4*)&dtwr[0] = *(const float4*)p;
        *(float4*)&dtwr[4] = *(const float4*)(p + 4);
    }
    const float bias = dtb[k * D_ + d];
    const float Dv = DsG[k * D_ + d];
    float A2[N_];
    {
        const float* ap = alg + ((size_t)k * D_ + d) * N_;
        #pragma unroll
        for (int j = 0; j < 4; ++j) {
            float4 a = *(const float4*)(ap + 4 * j);
            A2[4*j]   = -__expf(a.x) * LOG2E; A2[4*j+1] = -__expf(a.y) * LOG2E;
            A2[4*j+2] = -__expf(a.z) * LOG2E; A2[4*j+3] = -__expf(a.w) * LOG2E;
        }
    }
    float h[N_];
    {
        const float* hp = hinit + (((size_t)bk * NCH + ch) * D_ + d) * N_;
        #pragma unroll
        for (int j = 0; j < 4; ++j) {
            float4 v = *(const float4*)(hp + 4 * j);
            h[4*j] = v.x; h[4*j+1] = v.y; h[4*j+2] = v.z; h[4*j+3] = v.w;
        }
    }
    __syncthreads();

    #pragma unroll
    for (int l = 0; l < CHUNK; ++l) {
        float dv[R_];
        *(float4*)&dv[0] = *(const float4*)&dts_s[l * R_];
        *(float4*)&dv[4] = *(const float4*)&dts_s[l * R_ + 4];
        float s = bias;
        #pragma unroll
        for (int r = 0; r < R_; ++r) s = fmaf(dv[r], dtwr[r], s);
        const float e = FEXP2(s * LOG2E);
        const float dlt = (s > 15.f) ? s : __logf(1.f + e);
        const float xb = dlt * uu[l];
        float p0 = 0.f, p1 = 0.f;
        #pragma unroll
        for (int g = 0; g < 4; ++g) {
            const float4 bg = *(const float4*)&B_s[l * N_ + 4 * g];
            const float4 cg4 = *(const float4*)&C_s[l * N_ + 4 * g];
            h[4*g+0] = fmaf(FEXP2(dlt * A2[4*g+0]), h[4*g+0], xb * bg.x);
            p0 = fmaf(h[4*g+0], cg4.x, p0);
            h[4*g+1] = fmaf(FEXP2(dlt * A2[4*g+1]), h[4*g+1], xb * bg.y);
            p1 = fmaf(h[4*g+1], cg4.y, p1);
            h[4*g+2] = fmaf(FEXP2(dlt * A2[4*g+2]), h[4*g+2], xb * bg.z);
            p0 = fmaf(h[4*g+2], cg4.z, p0);
            h[4*g+3] = fmaf(FEXP2(dlt * A2[4*g+3]), h[4*g+3], xb * bg.w);
            p1 = fmaf(h[4*g+3], cg4.w, p1);
        }
        y_s[d * YS + l] = fmaf(uu[l], Dv, p0 + p1);
    }
    __syncthreads();

    #pragma unroll
    for (int p = 0; p < 8; ++p) {
        const int f = tid + p * 128;
        const int row = f >> 3, j4 = (f & 7) * 4;
        const float* yp = &y_s[row * YS + j4];
        float4 o; o.x = yp[0]; o.y = yp[1]; o.z = yp[2]; o.w = yp[3];
        *(float4*)(out + ((size_t)bk * D_ + row) * L_ + ch * CHUNK + j4) = o;
    }
}

extern "C" void kernel_launch(void* const* d_in, const int* in_sizes, int n_in,
                              void* d_out, int out_size, void* d_ws, size_t ws_size,
                              hipStream_t stream)
{
    const float* qx  = (const float*)d_in[0];
    const float* kv  = (const float*)d_in[1];
    const float* xw  = (const float*)d_in[2];
    const float* dtw = (const float*)d_in[3];
    const float* dtb = (const float*)d_in[4];
    const float* alg = (const float*)d_in[5];
    const float* Ds  = (const float*)d_in[6];
    float* out = (float*)d_out;

    const size_t sz_dts = (size_t)B_ * K_ * L_ * R_;        //   262,144
    const size_t sz_bc  = (size_t)B_ * K_ * L_ * N_;        //   524,288
    const size_t sz_h   = (size_t)B_ * K_ * NCH * D_ * N_;  // 2,097,152
    const size_t sz_ss  = (size_t)B_ * K_ * NCH * D_;       //   131,072
    const size_t need = (sz_dts + 2 * sz_bc + 2 * sz_h + sz_ss) * sizeof(float);
    if (ws_size < need) return;   // ~22.5 MB

    float* dts   = (float*)d_ws;
    float* BTp   = dts + sz_dts;
    float* CTp   = BTp + sz_bc;
    float* hend  = CTp + sz_bc;
    float* hinit = hend + sz_h;
    float* Ssm   = hinit + sz_h;

    kP_gemm<<<B_ * K_ * 32 * 2, 192, 0, stream>>>(qx, kv, xw, dts, BTp, CTp);
    k2_pass1<<<B_ * K_ * NCH, 128, 0, stream>>>(kv, dts, BTp, alg, dtw, dtb, hend, Ssm);
    k25_chain<<<256, 64, 0, stream>>>(alg, Ssm, hend, hinit);
    k3_pass2<<<B_ * K_ * NCH, 128, 0, stream>>>(kv, dts, BTp, CTp, alg, dtw, dtb, Ds, hinit, out);
}